// Round 2
// baseline (3078.986 us; speedup 1.0000x reference)
//
#include <hip/hip_runtime.h>
#include <cstdint>

// TransformerClassification: B=32, S=1024, E=1024, FF=1024, OUT=2, 2 identical blocks.
// R4: 256x256 8-wave GEMM, single-barrier 4-phase pipelined schedule:
//   per phase: barrier -> STAGE(1 half-tile) -> ds_reads(next phase frags) ->
//              setprio(1) 16xMFMA setprio(0) -> lgkmcnt(0) [P3: +vmcnt(2)]
// so LDS-read BW/latency hides under MFMA and barriers halve (4/K-tile).
// Epilogue bounces C through LDS (swizzled) -> 16B coalesced stores (kills the
// ~205MB partial-line RMW fetch seen in R3 counters).

#define AS1 __attribute__((address_space(1)))
#define AS3 __attribute__((address_space(3)))

typedef __attribute__((ext_vector_type(8))) short bf16x8;
typedef __attribute__((ext_vector_type(4))) float f32x4;
typedef __attribute__((ext_vector_type(4))) unsigned short us4;
typedef __attribute__((ext_vector_type(8))) unsigned short us8;

__device__ __forceinline__ unsigned short f2bf(float f) {
  unsigned int u = __builtin_bit_cast(unsigned int, f);
  u += 0x7fffu + ((u >> 16) & 1u);          // round-to-nearest-even
  return (unsigned short)(u >> 16);
}
__device__ __forceinline__ float bf2f(unsigned short h) {
  return __builtin_bit_cast(float, (unsigned int)h << 16);
}

__device__ __forceinline__ void gload_lds16(const void* g, void* l) {
  auto gp = reinterpret_cast<AS1 unsigned int*>(reinterpret_cast<uintptr_t>(g));
  auto lp = reinterpret_cast<AS3 unsigned int*>(reinterpret_cast<uintptr_t>(l));
  __builtin_amdgcn_global_load_lds(gp, lp, 16, 0, 0);
}

enum { M_BF16 = 0, M_RELU = 1, M_QKV = 2, M_SCBF = 3, M_RESID = 4 };

#define MFMA_QUAD(qi, qj)                                                          \
  do {                                                                             \
    _Pragma("unroll") for (int i2 = 0; i2 < 4; ++i2) {                             \
      _Pragma("unroll") for (int j2 = 0; j2 < 2; ++j2) {                           \
        f32x4& c = acc[(qi) * 4 + i2][(qj) * 2 + j2];                              \
        c = __builtin_amdgcn_mfma_f32_16x16x32_bf16(aF[(qi) * 4 + i2][0],          \
                                                    bF[(qj) * 2 + j2][0], c, 0, 0, 0); \
        c = __builtin_amdgcn_mfma_f32_16x16x32_bf16(aF[(qi) * 4 + i2][1],          \
                                                    bF[(qj) * 2 + j2][1], c, 0, 0, 0); \
      }                                                                            \
    }                                                                              \
  } while (0)

// C = A (MxK bf16 rm) * B^T (B is NxK bf16 rm), batched via blockIdx.z.
// 256x256 tile, 512 threads = 8 waves (2M x 4N), per-wave 128x64 output.
// BK=64, 2-slot LDS dbuf. Stage stream: B(g+1,h0)@P1, B(g+1,h1)@P2 -> other slot;
// A(g+2,h0)@P3, A(g+2,h1)@P4 -> current slot (its A-reads complete by P2's lgkm).
// vmcnt(2) at end of P3 retires B(g+1,*) and A(g+1,*) before P4 reads next-P1 frags.
template<int MODE>
__global__ __launch_bounds__(512, 2) void gemm_bt(
    const unsigned short* __restrict__ A, long long sAb,
    const unsigned short* __restrict__ B, long long sBb,
    const float* __restrict__ bias,
    const float* __restrict__ resid,
    float* __restrict__ outF,
    unsigned short* __restrict__ outBF,
    long long sOb, int N, int K, float scale)
{
  // 2 slots x (A[256][64] + B[256][64]) bf16 = 128 KiB; reused as C-bounce in epilogue
  __shared__ __align__(16) unsigned short lds[65536];
  const int t    = threadIdx.x;
  const int w    = t >> 6;
  const int lane = t & 63;
  const int quad = lane >> 4;
  const int l16  = lane & 15;
  const int l7   = l16 & 7;
  const int wm   = w >> 2;          // 0..1  (M half)
  const int wn   = w & 3;           // 0..3  (N quarter)
  const int bz   = blockIdx.z;
  const unsigned short* Ab = A + (long long)bz * sAb;
  const unsigned short* Bb = B + (long long)bz * sBb;
  const int m0 = blockIdx.y * 256;
  const int n0 = blockIdx.x * 256;

  // staging geometry: wave w covers rows {r*64 + w*8 + (lane>>3)} of a 128-row half.
  // Global source col pre-swizzled so linear LDS landing == swizzled layout.
  const int sr8  = lane >> 3;                       // 0..7
  const int gseg = ((lane & 7) ^ sr8) << 3;         // swizzled 8-elem segment
  const unsigned short* aSrc = Ab + (long long)(m0 + w * 8 + sr8) * K + gseg;
  const unsigned short* bSrc = Bb + (long long)(n0 + w * 8 + sr8) * K + gseg;
  const int ldsW = w << 9;                          // w*512 elems

  // read geometry (row&7 == l16&7 for all frag rows)
  const int aOff = (wm * 128 + l16) * 64;
  const int bOff = 16384 + (wn * 64 + l16) * 64;
  const int seg0 = (quad ^ l7) << 3;                // kk=0 segment (swizzled)
  const int seg1 = ((quad + 4) ^ l7) << 3;          // kk=1 segment

  const int NG = K >> 6;                            // K-tiles (16 for K=1024; even)

  const f32x4 zero = {0.f, 0.f, 0.f, 0.f};
  f32x4 acc[8][4];
#pragma unroll
  for (int i = 0; i < 8; ++i)
#pragma unroll
    for (int j = 0; j < 4; ++j) acc[i][j] = zero;

  bf16x8 aF[8][2];
  bf16x8 bF[4][2];

#define STAGE_A(kt, h, SL) do {                                                    \
    const unsigned short* _s = aSrc + (long long)(h) * 128 * K + (kt) * 64;        \
    unsigned short* _d = &lds[(SL) + ((h) << 13) + ldsW];                          \
    gload_lds16(_s, _d);                                                           \
    gload_lds16(_s + 64 * (long long)K, _d + 4096);                                \
  } while (0)
#define STAGE_B(kt, h, SL) do {                                                    \
    const unsigned short* _s = bSrc + (long long)(h) * 128 * K + (kt) * 64;        \
    unsigned short* _d = &lds[(SL) + 16384 + ((h) << 13) + ldsW];                  \
    gload_lds16(_s, _d);                                                           \
    gload_lds16(_s + 64 * (long long)K, _d + 4096);                                \
  } while (0)

#define READ_A03(SL)                                                               \
    _Pragma("unroll") for (int i2 = 0; i2 < 4; ++i2) {                             \
      aF[i2][0] = *(const bf16x8*)&lds[(SL) + aOff + i2 * 1024 + seg0];            \
      aF[i2][1] = *(const bf16x8*)&lds[(SL) + aOff + i2 * 1024 + seg1];            \
    }
#define READ_A47(SL)                                                               \
    _Pragma("unroll") for (int i2 = 0; i2 < 4; ++i2) {                             \
      aF[4 + i2][0] = *(const bf16x8*)&lds[(SL) + aOff + (4 + i2) * 1024 + seg0];  \
      aF[4 + i2][1] = *(const bf16x8*)&lds[(SL) + aOff + (4 + i2) * 1024 + seg1];  \
    }
#define READ_B01(SL)                                                               \
    _Pragma("unroll") for (int j2 = 0; j2 < 2; ++j2) {                             \
      bF[j2][0] = *(const bf16x8*)&lds[(SL) + bOff + j2 * 1024 + seg0];            \
      bF[j2][1] = *(const bf16x8*)&lds[(SL) + bOff + j2 * 1024 + seg1];            \
    }
#define READ_B23(SL)                                                               \
    _Pragma("unroll") for (int j2 = 0; j2 < 2; ++j2) {                             \
      bF[2 + j2][0] = *(const bf16x8*)&lds[(SL) + bOff + (2 + j2) * 1024 + seg0];  \
      bF[2 + j2][1] = *(const bf16x8*)&lds[(SL) + bOff + (2 + j2) * 1024 + seg1];  \
    }

  // Quadrant order per K-tile: P1=(0,0) P2=(0,1) P3=(1,0) P4=(1,1).
  // Per-phase pre-reads: P1->bF23, P2->aF47, P3->none, P4->aF03+bF01 (next tile).
  // P4's MFMA (aF47,bF23) is disjoint from the registers refilled for next-P1.
#define KTILE(g, CUR, OTH)                                                         \
  { /* P1: MFMA(0,0) uses aF03,bF01 (read last phase) */                           \
    __builtin_amdgcn_s_barrier();                                                  \
    if ((g) + 1 < NG) STAGE_B((g) + 1, 0, OTH);                                    \
    READ_B23(CUR)                                                                  \
    __builtin_amdgcn_s_setprio(1);                                                 \
    MFMA_QUAD(0, 0);                                                               \
    __builtin_amdgcn_s_setprio(0);                                                 \
    asm volatile("s_waitcnt lgkmcnt(0)" ::: "memory");                             \
  }                                                                                \
  { /* P2: MFMA(0,1) uses aF03,bF23 */                                             \
    __builtin_amdgcn_s_barrier();                                                  \
    if ((g) + 1 < NG) STAGE_B((g) + 1, 1, OTH);                                    \
    READ_A47(CUR)                                                                  \
    __builtin_amdgcn_s_setprio(1);                                                 \
    MFMA_QUAD(0, 1);                                                               \
    __builtin_amdgcn_s_setprio(0);                                                 \
    asm volatile("s_waitcnt lgkmcnt(0)" ::: "memory");                             \
  }                                                                                \
  { /* P3: MFMA(1,0) uses aF47,bF01 */                                             \
    __builtin_amdgcn_s_barrier();                                                  \
    if ((g) + 2 < NG) STAGE_A((g) + 2, 0, CUR);                                    \
    __builtin_amdgcn_s_setprio(1);                                                 \
    MFMA_QUAD(1, 0);                                                               \
    __builtin_amdgcn_s_setprio(0);                                                 \
    if ((g) + 2 < NG) {                                                            \
      asm volatile("s_waitcnt vmcnt(2) lgkmcnt(0)" ::: "memory");                  \
    } else {                                                                       \
      asm volatile("s_waitcnt vmcnt(0) lgkmcnt(0)" ::: "memory");                  \
    }                                                                              \
  }                                                                                \
  { /* P4: MFMA(1,1) uses aF47,bF23; refill aF03,bF01 from OTH for next tile */    \
    __builtin_amdgcn_s_barrier();                                                  \
    if ((g) + 2 < NG) STAGE_A((g) + 2, 1, CUR);                                    \
    if ((g) + 1 < NG) {                                                            \
      READ_A03(OTH)                                                                \
      READ_B01(OTH)                                                                \
    }                                                                              \
    __builtin_amdgcn_s_setprio(1);                                                 \
    MFMA_QUAD(1, 1);                                                               \
    __builtin_amdgcn_s_setprio(0);                                                 \
    asm volatile("s_waitcnt lgkmcnt(0)" ::: "memory");                             \
  }

  // ---- prologue: slot0 full (A0,B0) + A1 -> slot1; then first-phase fragments
  STAGE_A(0, 0, 0); STAGE_A(0, 1, 0); STAGE_B(0, 0, 0); STAGE_B(0, 1, 0);
  STAGE_A(1, 0, 32768); STAGE_A(1, 1, 32768);
  asm volatile("s_waitcnt vmcnt(4)" ::: "memory");   // slot0 landed; A1 in flight
  __builtin_amdgcn_s_barrier();
  READ_A03(0)
  READ_B01(0)
  asm volatile("s_waitcnt lgkmcnt(0)" ::: "memory");

#pragma unroll 1
  for (int g = 0; g < NG; g += 2) {
    KTILE(g, 0, 32768)
    KTILE(g + 1, 32768, 0)
  }

#undef KTILE
#undef STAGE_A
#undef STAGE_B

  // ---------------- Epilogue ----------------
  // C/D layout: col = lane&15, row = quad*4 + reg
  const int segq = (MODE == M_QKV) ? (n0 >> 10) : 0;   // block-uniform
  if (MODE == M_QKV && segq == 2) {
    // V transposed per batch: vT[b][d][s] (8B column writes, unchanged)
#pragma unroll
    for (int i = 0; i < 8; ++i) {
      const int mt = m0 + wm * 128 + i * 16 + quad * 4;
#pragma unroll
      for (int j = 0; j < 4; ++j) {
        const int nt = n0 + wn * 64 + j * 16 + l16;
        const int ntl = nt - 2048;
        const float bv = bias[nt];
        f32x4 d = acc[i][j];
        unsigned short* dst = outBF + 2LL * 33554432LL;
        us4 pk;
#pragma unroll
        for (int r = 0; r < 4; ++r) pk[r] = f2bf(d[r] + bv);
        const int b = mt >> 10;
        const int s = mt & 1023;
        *(us4*)&dst[(long long)b * 1048576 + (long long)ntl * 1024 + s] = pk;
      }
    }
  } else if (MODE == M_RESID) {
#pragma unroll
    for (int i = 0; i < 8; ++i) {
      const int mt = m0 + wm * 128 + i * 16 + quad * 4;
#pragma unroll
      for (int j = 0; j < 4; ++j) {
        const int nt = n0 + wn * 64 + j * 16 + l16;
        const float bv = bias[nt];
        f32x4 d = acc[i][j];
#pragma unroll
        for (int r = 0; r < 4; ++r) {
          const long long idx = (long long)(mt + r) * N + nt;
          outF[idx] = resid[idx] + d[r] + bv;
        }
      }
    }
  } else {
    // LDS bounce: C_lds[256][256] bf16 (=128KiB), 16B-seg swizzle col ^= (row&7)<<3.
    // Then 16B coalesced stores (full-line coverage, no partial-line RMW).
#pragma unroll
    for (int i = 0; i < 8; ++i) {
      const int lr0 = wm * 128 + i * 16 + quad * 4;
#pragma unroll
      for (int j = 0; j < 4; ++j) {
        const int colg = wn * 64 + j * 16 + l16;
        float bv = 0.0f;
        if (MODE == M_BF16 || MODE == M_RELU || MODE == M_QKV)
          bv = bias ? bias[n0 + colg] : 0.0f;
        f32x4 d = acc[i][j];
#pragma unroll
        for (int r = 0; r < 4; ++r) {
          float v;
          if (MODE == M_SCBF) v = d[r] * scale;
          else                v = d[r] + bv;
          if (MODE == M_RELU) v = fmaxf(v, 0.0f);
          const int lr = lr0 + r;
          lds[lr * 256 + (colg ^ ((lr & 7) << 3))] = f2bf(v);
        }
      }
    }
    __syncthreads();
    const int lr = t >> 1;
    const int cb = (t & 1) * 128;
#pragma unroll
    for (int k = 0; k < 16; ++k) {
      const int colg = cb + k * 8;
      us8 vv = *(const us8*)&lds[lr * 256 + (colg ^ ((lr & 7) << 3))];
      if (MODE == M_QKV) {
        unsigned short* dst = outBF + (long long)segq * 33554432LL;
        *(us8*)&dst[(long long)(m0 + lr) * 1024 + (n0 + colg - (segq << 10))] = vv;
      } else {
        *(us8*)&outBF[(long long)bz * sOb + (long long)(m0 + lr) * N + (n0 + colg)] = vv;
      }
    }
  }
}

// LayerNorm over rows of 1024. EMBED=1: v = 32*x + pe written to x1out; else read xin.
template<int EMBED>
__global__ __launch_bounds__(256) void ln_kernel(
    const float* __restrict__ xin, const float* __restrict__ pe,
    float* __restrict__ x1out,
    const float* __restrict__ g, const float* __restrict__ bb,
    unsigned short* __restrict__ hout)
{
  __shared__ float red[8];
  const long long row = blockIdx.x;
  const int t = threadIdx.x, lane = t & 63, w = t >> 6;
  float4 v = *(const float4*)(xin + row * 1024 + t * 4);
  if (EMBED) {
    const int s = (int)(row & 1023);
    float4 p = *(const float4*)(pe + (long long)s * 1024 + t * 4);
    v.x = 32.0f * v.x + p.x;
    v.y = 32.0f * v.y + p.y;
    v.z = 32.0f * v.z + p.z;
    v.w = 32.0f * v.w + p.w;
    *(float4*)(x1out + row * 1024 + t * 4) = v;
  }
  float sum = v.x + v.y + v.z + v.w;
  float sq  = v.x * v.x + v.y * v.y + v.z * v.z + v.w * v.w;
#pragma unroll
  for (int off = 32; off > 0; off >>= 1) {
    sum += __shfl_down(sum, off, 64);
    sq  += __shfl_down(sq,  off, 64);
  }
  if (lane == 0) { red[w] = sum; red[4 + w] = sq; }
  __syncthreads();
  sum = red[0] + red[1] + red[2] + red[3];
  sq  = red[4] + red[5] + red[6] + red[7];
  const float mu  = sum * (1.0f / 1024.0f);
  const float var = sq * (1.0f / 1024.0f) - mu * mu;
  const float rs  = rsqrtf(var + 1e-5f);
  float4 gg = *(const float4*)(g + t * 4);
  float4 bv = *(const float4*)(bb + t * 4);
  us4 h;
  h[0] = f2bf((v.x - mu) * rs * gg.x + bv.x);
  h[1] = f2bf((v.y - mu) * rs * gg.y + bv.y);
  h[2] = f2bf((v.z - mu) * rs * gg.z + bv.z);
  h[3] = f2bf((v.w - mu) * rs * gg.w + bv.w);
  *(us4*)(hout + row * 1024 + t * 4) = h;
}

// Softmax over rows of 1024: reads bf16 scores, writes fp32 w (d_out) + bf16 w.
__global__ __launch_bounds__(256) void softmax_kernel(
    const unsigned short* __restrict__ sbf,
    float* __restrict__ wout, unsigned short* __restrict__ wbf)
{
  __shared__ float red[8];
  const long long row = blockIdx.x;
  const int t = threadIdx.x, lane = t & 63, w = t >> 6;
  us4 sv = *(const us4*)(sbf + row * 1024 + t * 4);
  float4 v;
  v.x = bf2f(sv[0]); v.y = bf2f(sv[1]); v.z = bf2f(sv[2]); v.w = bf2f(sv[3]);
  float mx = fmaxf(fmaxf(v.x, v.y), fmaxf(v.z, v.w));
#pragma unroll
  for (int off = 32; off > 0; off >>= 1) mx = fmaxf(mx, __shfl_down(mx, off, 64));
  if (lane == 0) red[w] = mx;
  __syncthreads();
  mx = fmaxf(fmaxf(red[0], red[1]), fmaxf(red[2], red[3]));
  __syncthreads();
  const float e0 = __expf(v.x - mx), e1 = __expf(v.y - mx);
  const float e2 = __expf(v.z - mx), e3 = __expf(v.w - mx);
  float s = e0 + e1 + e2 + e3;
#pragma unroll
  for (int off = 32; off > 0; off >>= 1) s += __shfl_down(s, off, 64);
  if (lane == 0) red[w] = s;
  __syncthreads();
  s = red[0] + red[1] + red[2] + red[3];
  const float inv = 1.0f / s;
  float4 o; o.x = e0 * inv; o.y = e1 * inv; o.z = e2 * inv; o.w = e3 * inv;
  *(float4*)(wout + row * 1024 + t * 4) = o;
  us4 ob;
  ob[0] = f2bf(o.x); ob[1] = f2bf(o.y); ob[2] = f2bf(o.z); ob[3] = f2bf(o.w);
  *(us4*)(wbf + row * 1024 + t * 4) = ob;
}

// One prep kernel: bf16-convert all 6 weights (QKV packed [3072,1024]) + pack QKV bias.
__global__ __launch_bounds__(256) void prep_kernel(
    const float* __restrict__ Wq, const float* __restrict__ Wk, const float* __restrict__ Wv,
    const float* __restrict__ Wo, const float* __restrict__ W1, const float* __restrict__ W2,
    const float* __restrict__ bq, const float* __restrict__ bk, const float* __restrict__ bv,
    unsigned short* __restrict__ qkvw, unsigned short* __restrict__ Wo_bf,
    unsigned short* __restrict__ W1_bf, unsigned short* __restrict__ W2_bf,
    float* __restrict__ qkvb)
{
  const int y = blockIdx.y;
  const long long i = blockIdx.x * 256 + threadIdx.x;   // quad index, < 262144
  if (y == 6) {
    if (i < 768) {
      const float* src = (i < 256) ? bq : (i < 512) ? bk : bv;
      float4 v = *(const float4*)(src + (i & 255) * 4);
      *(float4*)(qkvb + i * 4) = v;
    }
    return;
  }
  const float* src;
  unsigned short* dst;
  switch (y) {
    case 0: src = Wq; dst = qkvw;            break;
    case 1: src = Wk; dst = qkvw + 1048576;  break;
    case 2: src = Wv; dst = qkvw + 2097152;  break;
    case 3: src = Wo; dst = Wo_bf;           break;
    case 4: src = W1; dst = W1_bf;           break;
    default: src = W2; dst = W2_bf;          break;
  }
  float4 v = *(const float4*)(src + i * 4);
  us4 o;
  o[0] = f2bf(v.x); o[1] = f2bf(v.y); o[2] = f2bf(v.z); o[3] = f2bf(v.w);
  *(us4*)(dst + i * 4) = o;
}

// logits[b,o] = x[b, s=0, :] . Wc[o,:] + bc[o]; 64 blocks, fp32.
__global__ __launch_bounds__(256) void logits_kernel(
    const float* __restrict__ x, const float* __restrict__ Wc,
    const float* __restrict__ bc, float* __restrict__ out)
{
  __shared__ float red[4];
  const int blk = blockIdx.x;           // b*2 + o
  const int b = blk >> 1, o = blk & 1;
  const int t = threadIdx.x, lane = t & 63, w = t >> 6;
  const float* xr = x + (long long)b * 1048576;
  const float* wr = Wc + o * 1024;
  float4 xv = *(const float4*)(xr + t * 4);
  float4 wv = *(const float4*)(wr + t * 4);
  float s = xv.x * wv.x + xv.y * wv.y + xv.z * wv.z + xv.w * wv.w;
#pragma unroll
  for (int off = 32; off > 0; off >>= 1) s += __shfl_down(s, off, 64);
  if (lane == 0) red[w] = s;
  __syncthreads();
  if (t == 0) out[blk] = red[0] + red[1] + red[2] + red[3] + bc[o];
}

extern "C" void kernel_launch(void* const* d_in, const int* in_sizes, int n_in,
                              void* d_out, int out_size, void* d_ws, size_t ws_size,
                              hipStream_t stream)
{
  const float* x    = (const float*)d_in[0];
  const float* pe   = (const float*)d_in[1];
  const float* ln1g = (const float*)d_in[2];
  const float* ln1b = (const float*)d_in[3];
  const float* Wq   = (const float*)d_in[4];
  const float* bq   = (const float*)d_in[5];
  const float* Wk   = (const float*)d_in[6];
  const float* bk   = (const float*)d_in[7];
  const float* Wv   = (const float*)d_in[8];
  const float* bv   = (const float*)d_in[9];
  const float* Wo   = (const float*)d_in[10];
  const float* bo   = (const float*)d_in[11];
  const float* ln2g = (const float*)d_in[12];
  const float* ln2b = (const float*)d_in[13];
  const float* W1   = (const float*)d_in[14];
  const float* b1   = (const float*)d_in[15];
  const float* W2   = (const float*)d_in[16];
  const float* b2   = (const float*)d_in[17];
  const float* Wc   = (const float*)d_in[18];
  const float* bc   = (const float*)d_in[19];
  float* out = (float*)d_out;

  // Workspace layout (~400 MiB):
  //   xbuf   128 MiB fp32 residual stream
  //   h_bf    64 MiB (LN out; reused as bf16 scores scratch)
  //   q_bf    64 MiB (QKV seg0; reused as attn out)
  //   k_bf    64 MiB (QKV seg1; reused as bf16 softmax weights)
  //   vT_bf   64 MiB (QKV seg2, transposed; reused as ff1)
  //   weights: QKV packed 6 MiB + Wo/W1/W2 2 MiB each + qkvb 12 KiB
  char* ws = (char*)d_ws;
  float*          xbuf  = (float*)ws;
  unsigned short* h_bf  = (unsigned short*)(ws + 134217728LL);
  unsigned short* q_bf  = (unsigned short*)(ws + 134217728LL + 1 * 67108864LL);
  unsigned short* k_bf  = (unsigned short*)(ws + 134217728LL + 2 * 67108864LL);
  unsigned short* vT_bf = (unsigned short*)(ws + 134217728LL + 3 * 67108864LL);
  unsigned short* wts   = (unsigned short*)(ws + 134217728LL + 4 * 67108864LL);
  unsigned short* QKV_bf = wts;                       // [3072,1024]
  unsigned short* Wo_bf  = wts + 3LL * 1048576;
  unsigned short* W1_bf  = wts + 4LL * 1048576;
  unsigned short* W2_bf  = wts + 5LL * 1048576;
  float*          qkvb   = (float*)(wts + 6LL * 1048576);  // [3072]
  unsigned short* sc_bf   = h_bf;
  unsigned short* w_bf    = k_bf;
  unsigned short* attn_bf = q_bf;
  unsigned short* ff1_bf  = vT_bf;

  const dim3 blk(256);
  const dim3 blkG(512);
  prep_kernel<<<dim3(1024, 7), blk, 0, stream>>>(Wq, Wk, Wv, Wo, W1, W2, bq, bk, bv,
                                                 QKV_bf, Wo_bf, W1_bf, W2_bf, qkvb);

  const dim3 gQKV(12, 128, 1);   // N=3072, M=32768, 256^2 tiles
  const dim3 gProj(4, 128, 1);   // N=1024, M=32768
  const dim3 gAttn(4, 4, 32);    // N=M=1024, batch=32

  for (int blkI = 0; blkI < 2; ++blkI) {
    float* wslot = out + 64 + (long long)blkI * 33554432LL;

    if (blkI == 0)
      ln_kernel<1><<<32768, blk, 0, stream>>>(x, pe, xbuf, ln1g, ln1b, h_bf);
    else
      ln_kernel<0><<<32768, blk, 0, stream>>>(xbuf, nullptr, nullptr, ln1g, ln1b, h_bf);

    gemm_bt<M_QKV><<<gQKV, blkG, 0, stream>>>(h_bf, 0, QKV_bf, 0, qkvb, nullptr,
                                              nullptr, q_bf, 0, 3072, 1024, 1.0f);

    gemm_bt<M_SCBF><<<gAttn, blkG, 0, stream>>>(q_bf, 1048576, k_bf, 1048576, nullptr,
                                                nullptr, nullptr, sc_bf, 1048576,
                                                1024, 1024, 0.03125f);
    softmax_kernel<<<32768, blk, 0, stream>>>(sc_bf, wslot, w_bf);

    gemm_bt<M_BF16><<<gAttn, blkG, 0, stream>>>(w_bf, 1048576, vT_bf, 1048576, nullptr,
                                                nullptr, nullptr, attn_bf, 1048576,
                                                1024, 1024, 1.0f);
    gemm_bt<M_RESID><<<gProj, blkG, 0, stream>>>(attn_bf, 0, Wo_bf, 0, bo, xbuf,
                                                 xbuf, nullptr, 0, 1024, 1024, 1.0f);

    ln_kernel<0><<<32768, blk, 0, stream>>>(xbuf, nullptr, nullptr, ln2g, ln2b, h_bf);
    gemm_bt<M_RELU><<<gProj, blkG, 0, stream>>>(h_bf, 0, W1_bf, 0, b1, nullptr,
                                                nullptr, ff1_bf, 0, 1024, 1024, 1.0f);
    gemm_bt<M_RESID><<<gProj, blkG, 0, stream>>>(ff1_bf, 0, W2_bf, 0, b2, xbuf,
                                                 xbuf, nullptr, 0, 1024, 1024, 1.0f);
  }

  logits_kernel<<<64, blk, 0, stream>>>(xbuf, Wc, bc, out);
  (void)in_sizes; (void)n_in; (void)out_size; (void)ws_size;
}

// Round 6
// 2153.018 us; speedup vs baseline: 1.4301x; 1.4301x over previous
//
#include <hip/hip_runtime.h>
#include <cstdint>

// TransformerClassification: B=32, S=1024, E=1024, FF=1024, OUT=2, 2 identical blocks.
// R5 (resubmit x3; R3/R4/R5 benches were broker timeouts): 256x256 8-wave GEMM.
// K-loop = R3's proven phase structure (reads -> stage -> barrier -> lgkm(0) ->
// setprio MFMA -> barrier), with deeper prefetch: P1 stages B(g+1,h1), P3
// A(g+2,h0), P4 A(g+2,h1)+B(g+2,h0); gate vmcnt(6) at P4 (every load has
// >=3-phase issue-to-wait distance; no HBM-latency stall). Epilogue: LDS bounce,
// wave = 2 full 512B rows (real full-line stores); V-segment transposed out of
// the bounce (kills scattered-8B vT RMW).

#define AS1 __attribute__((address_space(1)))
#define AS3 __attribute__((address_space(3)))

typedef __attribute__((ext_vector_type(8))) short bf16x8;
typedef __attribute__((ext_vector_type(4))) float f32x4;
typedef __attribute__((ext_vector_type(4))) unsigned short us4;
typedef __attribute__((ext_vector_type(8))) unsigned short us8;

__device__ __forceinline__ unsigned short f2bf(float f) {
  unsigned int u = __builtin_bit_cast(unsigned int, f);
  u += 0x7fffu + ((u >> 16) & 1u);          // round-to-nearest-even
  return (unsigned short)(u >> 16);
}
__device__ __forceinline__ float bf2f(unsigned short h) {
  return __builtin_bit_cast(float, (unsigned int)h << 16);
}

__device__ __forceinline__ void gload_lds16(const void* g, void* l) {
  auto gp = reinterpret_cast<AS1 unsigned int*>(reinterpret_cast<uintptr_t>(g));
  auto lp = reinterpret_cast<AS3 unsigned int*>(reinterpret_cast<uintptr_t>(l));
  __builtin_amdgcn_global_load_lds(gp, lp, 16, 0, 0);
}

enum { M_BF16 = 0, M_RELU = 1, M_QKV = 2, M_SCBF = 3, M_RESID = 4 };

#define MFMA_QUAD(qi, qj)                                                          \
  do {                                                                             \
    _Pragma("unroll") for (int i2 = 0; i2 < 4; ++i2) {                             \
      _Pragma("unroll") for (int j2 = 0; j2 < 2; ++j2) {                           \
        f32x4& c = acc[(qi) * 4 + i2][(qj) * 2 + j2];                              \
        c = __builtin_amdgcn_mfma_f32_16x16x32_bf16(aF[(qi) * 4 + i2][0],          \
                                                    bF[(qj) * 2 + j2][0], c, 0, 0, 0); \
        c = __builtin_amdgcn_mfma_f32_16x16x32_bf16(aF[(qi) * 4 + i2][1],          \
                                                    bF[(qj) * 2 + j2][1], c, 0, 0, 0); \
      }                                                                            \
    }                                                                              \
  } while (0)

// C = A (MxK bf16 rm) * B^T (B is NxK bf16 rm), batched via blockIdx.z.
// 256x256 tile, 512 threads = 8 waves (2M x 4N), per-wave 128x64 output.
// BK=64, 2-slot LDS dbuf. Steady-state outstanding vmem = 6 gloads
// {A(g+2,h0),A(g+2,h1),B(g+2,h0)}; vmcnt(6) at P4 retires everything issued
// through this tile's P1 (incl. B(g+1,h1)) before next tile's reads.
template<int MODE>
__global__ __launch_bounds__(512, 2) void gemm_bt(
    const unsigned short* __restrict__ A, long long sAb,
    const unsigned short* __restrict__ B, long long sBb,
    const float* __restrict__ bias,
    const float* __restrict__ resid,
    float* __restrict__ outF,
    unsigned short* __restrict__ outBF,
    long long sOb, int N, int K, float scale)
{
  // 2 slots x (A[256][64] + B[256][64]) bf16 = 128 KiB; reused as C-bounce in epilogue
  __shared__ __align__(16) unsigned short lds[65536];
  const int t    = threadIdx.x;
  const int w    = t >> 6;
  const int lane = t & 63;
  const int quad = lane >> 4;
  const int l16  = lane & 15;
  const int l7   = l16 & 7;
  const int wm   = w >> 2;          // 0..1  (M half)
  const int wn   = w & 3;           // 0..3  (N quarter)
  const int bz   = blockIdx.z;
  const unsigned short* Ab = A + (long long)bz * sAb;
  const unsigned short* Bb = B + (long long)bz * sBb;
  const int m0 = blockIdx.y * 256;
  const int n0 = blockIdx.x * 256;

  // staging geometry: wave w covers rows {r*64 + w*8 + (lane>>3)} of a 128-row half.
  // Global source col pre-swizzled so linear LDS landing == swizzled layout.
  const int sr8  = lane >> 3;                       // 0..7
  const int gseg = ((lane & 7) ^ sr8) << 3;         // swizzled 8-elem segment
  const unsigned short* aSrc = Ab + (long long)(m0 + w * 8 + sr8) * K + gseg;
  const unsigned short* bSrc = Bb + (long long)(n0 + w * 8 + sr8) * K + gseg;
  const int ldsW = w << 9;                          // w*512 elems

  // read geometry (row&7 == l16&7 for all frag rows)
  const int aOff = (wm * 128 + l16) * 64;
  const int bOff = 16384 + (wn * 64 + l16) * 64;
  const int seg0 = (quad ^ l7) << 3;                // kk=0 segment (swizzled)
  const int seg1 = ((quad + 4) ^ l7) << 3;          // kk=1 segment

  const int NG = K >> 6;                            // K-tiles (16 for K=1024; even)

  const f32x4 zero = {0.f, 0.f, 0.f, 0.f};
  f32x4 acc[8][4];
#pragma unroll
  for (int i = 0; i < 8; ++i)
#pragma unroll
    for (int j = 0; j < 4; ++j) acc[i][j] = zero;

  bf16x8 aF[8][2];
  bf16x8 bF[4][2];

#define STAGE_A(kt, h, SL) do {                                                    \
    const unsigned short* _s = aSrc + (long long)(h) * 128 * K + (kt) * 64;        \
    unsigned short* _d = &lds[(SL) + ((h) << 13) + ldsW];                          \
    gload_lds16(_s, _d);                                                           \
    gload_lds16(_s + 64 * (long long)K, _d + 4096);                                \
  } while (0)
#define STAGE_B(kt, h, SL) do {                                                    \
    const unsigned short* _s = bSrc + (long long)(h) * 128 * K + (kt) * 64;        \
    unsigned short* _d = &lds[(SL) + 16384 + ((h) << 13) + ldsW];                  \
    gload_lds16(_s, _d);                                                           \
    gload_lds16(_s + 64 * (long long)K, _d + 4096);                                \
  } while (0)

#define READ_A03(SL)                                                               \
    _Pragma("unroll") for (int i2 = 0; i2 < 4; ++i2) {                             \
      aF[i2][0] = *(const bf16x8*)&lds[(SL) + aOff + i2 * 1024 + seg0];            \
      aF[i2][1] = *(const bf16x8*)&lds[(SL) + aOff + i2 * 1024 + seg1];            \
    }
#define READ_A47(SL)                                                               \
    _Pragma("unroll") for (int i2 = 0; i2 < 4; ++i2) {                             \
      aF[4 + i2][0] = *(const bf16x8*)&lds[(SL) + aOff + (4 + i2) * 1024 + seg0];  \
      aF[4 + i2][1] = *(const bf16x8*)&lds[(SL) + aOff + (4 + i2) * 1024 + seg1];  \
    }
#define READ_B01(SL)                                                               \
    _Pragma("unroll") for (int j2 = 0; j2 < 2; ++j2) {                             \
      bF[j2][0] = *(const bf16x8*)&lds[(SL) + bOff + j2 * 1024 + seg0];            \
      bF[j2][1] = *(const bf16x8*)&lds[(SL) + bOff + j2 * 1024 + seg1];            \
    }
#define READ_B23(SL)                                                               \
    _Pragma("unroll") for (int j2 = 0; j2 < 2; ++j2) {                             \
      bF[2 + j2][0] = *(const bf16x8*)&lds[(SL) + bOff + (2 + j2) * 1024 + seg0];  \
      bF[2 + j2][1] = *(const bf16x8*)&lds[(SL) + bOff + (2 + j2) * 1024 + seg1];  \
    }

  // R3-proven phase shape; only stage placement/gate changed.
  // MFMA order: P1 (0,0), P2 (1,0), P3 (1,1), P4 (0,1).
  // Region liveness: A(g) reads end P2; B(g) reads end P3 -> stages into CUR at
  // P3 (A.h0) and P4 (A.h1, B.h0) are barrier-separated WAR-safe; B(g+1,h1) into
  // OTH at P1 overwrites B(g-1,h1), dead since (g-1).P3.
#define KTILE(g, CUR, OTH)                                                         \
  { /* P1 */                                                                       \
    READ_A03(CUR)                                                                  \
    READ_B01(CUR)                                                                  \
    if ((g) + 1 < NG) STAGE_B((g) + 1, 1, OTH);                                    \
    __builtin_amdgcn_s_barrier();                                                  \
    asm volatile("s_waitcnt lgkmcnt(0)" ::: "memory");                             \
    __builtin_amdgcn_s_setprio(1);                                                 \
    MFMA_QUAD(0, 0);                                                               \
    __builtin_amdgcn_s_setprio(0);                                                 \
    __builtin_amdgcn_s_barrier();                                                  \
  }                                                                                \
  { /* P2 */                                                                       \
    READ_A47(CUR)                                                                  \
    __builtin_amdgcn_s_barrier();                                                  \
    asm volatile("s_waitcnt lgkmcnt(0)" ::: "memory");                             \
    __builtin_amdgcn_s_setprio(1);                                                 \
    MFMA_QUAD(1, 0);                                                               \
    __builtin_amdgcn_s_setprio(0);                                                 \
    __builtin_amdgcn_s_barrier();                                                  \
  }                                                                                \
  { /* P3 */                                                                       \
    READ_B23(CUR)                                                                  \
    if ((g) + 2 < NG) STAGE_A((g) + 2, 0, CUR);                                    \
    __builtin_amdgcn_s_barrier();                                                  \
    asm volatile("s_waitcnt lgkmcnt(0)" ::: "memory");                             \
    __builtin_amdgcn_s_setprio(1);                                                 \
    MFMA_QUAD(1, 1);                                                               \
    __builtin_amdgcn_s_setprio(0);                                                 \
    __builtin_amdgcn_s_barrier();                                                  \
  }                                                                                \
  { /* P4 */                                                                       \
    if ((g) + 2 < NG) { STAGE_A((g) + 2, 1, CUR); STAGE_B((g) + 2, 0, CUR); }      \
    if ((g) + 2 < NG) {                                                            \
      asm volatile("s_waitcnt vmcnt(6)" ::: "memory");                             \
    } else {                                                                       \
      asm volatile("s_waitcnt vmcnt(0)" ::: "memory");                             \
    }                                                                              \
    __builtin_amdgcn_s_barrier();                                                  \
    __builtin_amdgcn_s_setprio(1);                                                 \
    MFMA_QUAD(0, 1);                                                               \
    __builtin_amdgcn_s_setprio(0);                                                 \
    __builtin_amdgcn_s_barrier();                                                  \
  }

  // ---- prologue: slot0 full; slot1 gets A(1) both halves + B(1,h0).
  // Outstanding after = 14 gloads; vmcnt(6) retires A0,B0 (8), keeps the 6
  // steady-state in-flight ones.
  STAGE_A(0, 0, 0); STAGE_A(0, 1, 0); STAGE_B(0, 0, 0); STAGE_B(0, 1, 0);
  STAGE_A(1, 0, 32768); STAGE_A(1, 1, 32768); STAGE_B(1, 0, 32768);
  asm volatile("s_waitcnt vmcnt(6)" ::: "memory");
  __builtin_amdgcn_s_barrier();

#pragma unroll 1
  for (int g = 0; g < NG; g += 2) {
    KTILE(g, 0, 32768)
    KTILE(g + 1, 32768, 0)
  }

#undef KTILE
#undef STAGE_A
#undef STAGE_B

  // ---------------- Epilogue ----------------
  // C/D layout: col = lane&15, row = quad*4 + reg
  const int segq = (MODE == M_QKV) ? (n0 >> 10) : 0;   // block-uniform
  if (MODE == M_RESID) {
    // fp32 residual add; per instruction 16 lanes x 4B = 64B full lines per row-quad
#pragma unroll
    for (int i = 0; i < 8; ++i) {
      const int mt = m0 + wm * 128 + i * 16 + quad * 4;
#pragma unroll
      for (int j = 0; j < 4; ++j) {
        const int nt = n0 + wn * 64 + j * 16 + l16;
        const float bv = bias[nt];
        f32x4 d = acc[i][j];
#pragma unroll
        for (int r = 0; r < 4; ++r) {
          const long long idx = (long long)(mt + r) * N + nt;
          outF[idx] = resid[idx] + d[r] + bv;
        }
      }
    }
  } else {
    // LDS bounce: C_lds[256][256] bf16 (=128KiB), 16B-seg swizzle col ^= (row&7)<<3
#pragma unroll
    for (int i = 0; i < 8; ++i) {
      const int lr0 = wm * 128 + i * 16 + quad * 4;
#pragma unroll
      for (int j = 0; j < 4; ++j) {
        const int colg = wn * 64 + j * 16 + l16;
        float bv = 0.0f;
        if (MODE == M_BF16 || MODE == M_RELU || MODE == M_QKV)
          bv = bias ? bias[n0 + colg] : 0.0f;
        f32x4 d = acc[i][j];
#pragma unroll
        for (int r = 0; r < 4; ++r) {
          float v;
          if (MODE == M_SCBF) v = d[r] * scale;
          else                v = d[r] + bv;
          if (MODE == M_RELU) v = fmaxf(v, 0.0f);
          const int lr = lr0 + r;
          lds[lr * 256 + (colg ^ ((lr & 7) << 3))] = f2bf(v);
        }
      }
    }
    __syncthreads();
    if (MODE == M_QKV && segq == 2) {
      // V transposed: vT[b][d][s]. Column-gather from bounce (2-way banks = free);
      // each thread emits 16 consecutive us8 along s (256B contiguous run).
      const int dl = t & 255;
      const int sh = t >> 8;                 // 0/1 -> s half
      unsigned short* dst = outBF + 2LL * 33554432LL
                          + (long long)(m0 >> 10) * 1048576
                          + (long long)((n0 & 1023) + dl) * 1024 + (m0 & 1023);
#pragma unroll
      for (int k = 0; k < 16; ++k) {
        const int s0 = sh * 128 + k * 8;
        us8 vv;
#pragma unroll
        for (int i = 0; i < 8; ++i)
          vv[i] = lds[(s0 + i) * 256 + (dl ^ (((s0 + i) & 7) << 3))];
        *(us8*)&dst[s0] = vv;
      }
    } else {
      // wave = 2 full rows of 512B: lanes 0-31 -> row r segs 0-31, lanes 32-63 -> r+1
#pragma unroll
      for (int k = 0; k < 16; ++k) {
        const int lr = k * 16 + (t >> 5);
        const int colg = (t & 31) * 8;
        us8 vv = *(const us8*)&lds[lr * 256 + (colg ^ ((lr & 7) << 3))];
        if (MODE == M_QKV) {
          unsigned short* dst = outBF + (long long)segq * 33554432LL;
          *(us8*)&dst[(long long)(m0 + lr) * 1024 + (n0 - (segq << 10)) + colg] = vv;
        } else {
          *(us8*)&outBF[(long long)bz * sOb + (long long)(m0 + lr) * N + (n0 + colg)] = vv;
        }
      }
    }
  }
}

// LayerNorm over rows of 1024. EMBED=1: v = 32*x + pe written to x1out; else read xin.
template<int EMBED>
__global__ __launch_bounds__(256) void ln_kernel(
    const float* __restrict__ xin, const float* __restrict__ pe,
    float* __restrict__ x1out,
    const float* __restrict__ g, const float* __restrict__ bb,
    unsigned short* __restrict__ hout)
{
  __shared__ float red[8];
  const long long row = blockIdx.x;
  const int t = threadIdx.x, lane = t & 63, w = t >> 6;
  float4 v = *(const float4*)(xin + row * 1024 + t * 4);
  if (EMBED) {
    const int s = (int)(row & 1023);
    float4 p = *(const float4*)(pe + (long long)s * 1024 + t * 4);
    v.x = 32.0f * v.x + p.x;
    v.y = 32.0f * v.y + p.y;
    v.z = 32.0f * v.z + p.z;
    v.w = 32.0f * v.w + p.w;
    *(float4*)(x1out + row * 1024 + t * 4) = v;
  }
  float sum = v.x + v.y + v.z + v.w;
  float sq  = v.x * v.x + v.y * v.y + v.z * v.z + v.w * v.w;
#pragma unroll
  for (int off = 32; off > 0; off >>= 1) {
    sum += __shfl_down(sum, off, 64);
    sq  += __shfl_down(sq,  off, 64);
  }
  if (lane == 0) { red[w] = sum; red[4 + w] = sq; }
  __syncthreads();
  sum = red[0] + red[1] + red[2] + red[3];
  sq  = red[4] + red[5] + red[6] + red[7];
  const float mu  = sum * (1.0f / 1024.0f);
  const float var = sq * (1.0f / 1024.0f) - mu * mu;
  const float rs  = rsqrtf(var + 1e-5f);
  float4 gg = *(const float4*)(g + t * 4);
  float4 bv = *(const float4*)(bb + t * 4);
  us4 h;
  h[0] = f2bf((v.x - mu) * rs * gg.x + bv.x);
  h[1] = f2bf((v.y - mu) * rs * gg.y + bv.y);
  h[2] = f2bf((v.z - mu) * rs * gg.z + bv.z);
  h[3] = f2bf((v.w - mu) * rs * gg.w + bv.w);
  *(us4*)(hout + row * 1024 + t * 4) = h;
}

// Softmax over rows of 1024: reads bf16 scores, writes fp32 w (d_out) + bf16 w.
__global__ __launch_bounds__(256) void softmax_kernel(
    const unsigned short* __restrict__ sbf,
    float* __restrict__ wout, unsigned short* __restrict__ wbf)
{
  __shared__ float red[8];
  const long long row = blockIdx.x;
  const int t = threadIdx.x, lane = t & 63, w = t >> 6;
  us4 sv = *(const us4*)(sbf + row * 1024 + t * 4);
  float4 v;
  v.x = bf2f(sv[0]); v.y = bf2f(sv[1]); v.z = bf2f(sv[2]); v.w = bf2f(sv[3]);
  float mx = fmaxf(fmaxf(v.x, v.y), fmaxf(v.z, v.w));
#pragma unroll
  for (int off = 32; off > 0; off >>= 1) mx = fmaxf(mx, __shfl_down(mx, off, 64));
  if (lane == 0) red[w] = mx;
  __syncthreads();
  mx = fmaxf(fmaxf(red[0], red[1]), fmaxf(red[2], red[3]));
  __syncthreads();
  const float e0 = __expf(v.x - mx), e1 = __expf(v.y - mx);
  const float e2 = __expf(v.z - mx), e3 = __expf(v.w - mx);
  float s = e0 + e1 + e2 + e3;
#pragma unroll
  for (int off = 32; off > 0; off >>= 1) s += __shfl_down(s, off, 64);
  if (lane == 0) red[w] = s;
  __syncthreads();
  s = red[0] + red[1] + red[2] + red[3];
  const float inv = 1.0f / s;
  float4 o; o.x = e0 * inv; o.y = e1 * inv; o.z = e2 * inv; o.w = e3 * inv;
  *(float4*)(wout + row * 1024 + t * 4) = o;
  us4 ob;
  ob[0] = f2bf(o.x); ob[1] = f2bf(o.y); ob[2] = f2bf(o.z); ob[3] = f2bf(o.w);
  *(us4*)(wbf + row * 1024 + t * 4) = ob;
}

// One prep kernel: bf16-convert all 6 weights (QKV packed [3072,1024]) + pack QKV bias.
__global__ __launch_bounds__(256) void prep_kernel(
    const float* __restrict__ Wq, const float* __restrict__ Wk, const float* __restrict__ Wv,
    const float* __restrict__ Wo, const float* __restrict__ W1, const float* __restrict__ W2,
    const float* __restrict__ bq, const float* __restrict__ bk, const float* __restrict__ bv,
    unsigned short* __restrict__ qkvw, unsigned short* __restrict__ Wo_bf,
    unsigned short* __restrict__ W1_bf, unsigned short* __restrict__ W2_bf,
    float* __restrict__ qkvb)
{
  const int y = blockIdx.y;
  const long long i = blockIdx.x * 256 + threadIdx.x;   // quad index, < 262144
  if (y == 6) {
    if (i < 768) {
      const float* src = (i < 256) ? bq : (i < 512) ? bk : bv;
      float4 v = *(const float4*)(src + (i & 255) * 4);
      *(float4*)(qkvb + i * 4) = v;
    }
    return;
  }
  const float* src;
  unsigned short* dst;
  switch (y) {
    case 0: src = Wq; dst = qkvw;            break;
    case 1: src = Wk; dst = qkvw + 1048576;  break;
    case 2: src = Wv; dst = qkvw + 2097152;  break;
    case 3: src = Wo; dst = Wo_bf;           break;
    case 4: src = W1; dst = W1_bf;           break;
    default: src = W2; dst = W2_bf;          break;
  }
  float4 v = *(const float4*)(src + i * 4);
  us4 o;
  o[0] = f2bf(v.x); o[1] = f2bf(v.y); o[2] = f2bf(v.z); o[3] = f2bf(v.w);
  *(us4*)(dst + i * 4) = o;
}

// logits[b,o] = x[b, s=0, :] . Wc[o,:] + bc[o]; 64 blocks, fp32.
__global__ __launch_bounds__(256) void logits_kernel(
    const float* __restrict__ x, const float* __restrict__ Wc,
    const float* __restrict__ bc, float* __restrict__ out)
{
  __shared__ float red[4];
  const int blk = blockIdx.x;           // b*2 + o
  const int b = blk >> 1, o = blk & 1;
  const int t = threadIdx.x, lane = t & 63, w = t >> 6;
  const float* xr = x + (long long)b * 1048576;
  const float* wr = Wc + o * 1024;
  float4 xv = *(const float4*)(xr + t * 4);
  float4 wv = *(const float4*)(wr + t * 4);
  float s = xv.x * wv.x + xv.y * wv.y + xv.z * wv.z + xv.w * wv.w;
#pragma unroll
  for (int off = 32; off > 0; off >>= 1) s += __shfl_down(s, off, 64);
  if (lane == 0) red[w] = s;
  __syncthreads();
  if (t == 0) out[blk] = red[0] + red[1] + red[2] + red[3] + bc[o];
}

extern "C" void kernel_launch(void* const* d_in, const int* in_sizes, int n_in,
                              void* d_out, int out_size, void* d_ws, size_t ws_size,
                              hipStream_t stream)
{
  const float* x    = (const float*)d_in[0];
  const float* pe   = (const float*)d_in[1];
  const float* ln1g = (const float*)d_in[2];
  const float* ln1b = (const float*)d_in[3];
  const float* Wq   = (const float*)d_in[4];
  const float* bq   = (const float*)d_in[5];
  const float* Wk   = (const float*)d_in[6];
  const float* bk   = (const float*)d_in[7];
  const float* Wv   = (const float*)d_in[8];
  const float* bv   = (const float*)d_in[9];
  const float* Wo   = (const float*)d_in[10];
  const float* bo   = (const float*)d_in[11];
  const float* ln2g = (const float*)d_in[12];
  const float* ln2b = (const float*)d_in[13];
  const float* W1   = (const float*)d_in[14];
  const float* b1   = (const float*)d_in[15];
  const float* W2   = (const float*)d_in[16];
  const float* b2   = (const float*)d_in[17];
  const float* Wc   = (const float*)d_in[18];
  const float* bc   = (const float*)d_in[19];
  float* out = (float*)d_out;

  // Workspace layout (~400 MiB):
  //   xbuf   128 MiB fp32 residual stream
  //   h_bf    64 MiB (LN out; reused as bf16 scores scratch)
  //   q_bf    64 MiB (QKV seg0; reused as attn out)
  //   k_bf    64 MiB (QKV seg1; reused as bf16 softmax weights)
  //   vT_bf   64 MiB (QKV seg2, transposed; reused as ff1)
  //   weights: QKV packed 6 MiB + Wo/W1/W2 2 MiB each + qkvb 12 KiB
  char* ws = (char*)d_ws;
  float*          xbuf  = (float*)ws;
  unsigned short* h_bf  = (unsigned short*)(ws + 134217728LL);
  unsigned short* q_bf  = (unsigned short*)(ws + 134217728LL + 1 * 67108864LL);
  unsigned short* k_bf  = (unsigned short*)(ws + 134217728LL + 2 * 67108864LL);
  unsigned short* vT_bf = (unsigned short*)(ws + 134217728LL + 3 * 67108864LL);
  unsigned short* wts   = (unsigned short*)(ws + 134217728LL + 4 * 67108864LL);
  unsigned short* QKV_bf = wts;                       // [3072,1024]
  unsigned short* Wo_bf  = wts + 3LL * 1048576;
  unsigned short* W1_bf  = wts + 4LL * 1048576;
  unsigned short* W2_bf  = wts + 5LL * 1048576;
  float*          qkvb   = (float*)(wts + 6LL * 1048576);  // [3072]
  unsigned short* sc_bf   = h_bf;
  unsigned short* w_bf    = k_bf;
  unsigned short* attn_bf = q_bf;
  unsigned short* ff1_bf  = vT_bf;

  const dim3 blk(256);
  const dim3 blkG(512);
  prep_kernel<<<dim3(1024, 7), blk, 0, stream>>>(Wq, Wk, Wv, Wo, W1, W2, bq, bk, bv,
                                                 QKV_bf, Wo_bf, W1_bf, W2_bf, qkvb);

  const dim3 gQKV(12, 128, 1);   // N=3072, M=32768, 256^2 tiles
  const dim3 gProj(4, 128, 1);   // N=1024, M=32768
  const dim3 gAttn(4, 4, 32);    // N=M=1024, batch=32

  for (int blkI = 0; blkI < 2; ++blkI) {
    float* wslot = out + 64 + (long long)blkI * 33554432LL;

    if (blkI == 0)
      ln_kernel<1><<<32768, blk, 0, stream>>>(x, pe, xbuf, ln1g, ln1b, h_bf);
    else
      ln_kernel<0><<<32768, blk, 0, stream>>>(xbuf, nullptr, nullptr, ln1g, ln1b, h_bf);

    gemm_bt<M_QKV><<<gQKV, blkG, 0, stream>>>(h_bf, 0, QKV_bf, 0, qkvb, nullptr,
                                              nullptr, q_bf, 0, 3072, 1024, 1.0f);

    gemm_bt<M_SCBF><<<gAttn, blkG, 0, stream>>>(q_bf, 1048576, k_bf, 1048576, nullptr,
                                                nullptr, nullptr, sc_bf, 1048576,
                                                1024, 1024, 0.03125f);
    softmax_kernel<<<32768, blk, 0, stream>>>(sc_bf, wslot, w_bf);

    gemm_bt<M_BF16><<<gAttn, blkG, 0, stream>>>(w_bf, 1048576, vT_bf, 1048576, nullptr,
                                                nullptr, nullptr, attn_bf, 1048576,
                                                1024, 1024, 1.0f);
    gemm_bt<M_RESID><<<gProj, blkG, 0, stream>>>(attn_bf, 0, Wo_bf, 0, bo, xbuf,
                                                 xbuf, nullptr, 0, 1024, 1024, 1.0f);

    ln_kernel<0><<<32768, blk, 0, stream>>>(xbuf, nullptr, nullptr, ln2g, ln2b, h_bf);
    gemm_bt<M_RELU><<<gProj, blkG, 0, stream>>>(h_bf, 0, W1_bf, 0, b1, nullptr,
                                                nullptr, ff1_bf, 0, 1024, 1024, 1.0f);
    gemm_bt<M_RESID><<<gProj, blkG, 0, stream>>>(ff1_bf, 0, W2_bf, 0, b2, xbuf,
                                                 xbuf, nullptr, 0, 1024, 1024, 1.0f);
  }

  logits_kernel<<<64, blk, 0, stream>>>(xbuf, Wc, bc, out);
  (void)in_sizes; (void)n_in; (void)out_size; (void)ws_size;
}